// Round 4
// baseline (8626.089 us; speedup 1.0000x reference)
//
#include <hip/hip_runtime.h>
#include <hip/hip_bf16.h>

typedef __hip_bfloat16 bf16;

#define B_   64
#define F_   2048
#define P_   196
#define T_   25
#define E_   512
#define H_   512
#define A_   512
#define V_   30000

__device__ __forceinline__ float b2f(bf16 x) { return __bfloat162float(x); }
__device__ __forceinline__ bf16 f2b(float x) { return __float2bfloat16(x); }

__device__ __forceinline__ float wave_reduce(float v) {
    #pragma unroll
    for (int off = 32; off; off >>= 1) v += __shfl_down(v, off);
    return v;
}

// mean over P (axis=2): meanf[b*F+f] = mean_p cnn[(b*F+f)*P + p]
__global__ void k_mean(const float* __restrict__ cnn, float* __restrict__ meanf) {
    int wave = (blockIdx.x * blockDim.x + threadIdx.x) >> 6;
    int lane = threadIdx.x & 63;
    if (wave >= B_ * F_) return;
    const float* row = cnn + (size_t)wave * P_;
    float acc = 0.f;
    for (int p = lane; p < P_; p += 64) acc += row[p];
    acc = wave_reduce(acc);
    if (lane == 0) meanf[wave] = acc * (1.0f / P_);
}

// h0[b,h] = meanf[b,:] @ W_init[:,h] + b_init[h]
__global__ void k_h0(const float* __restrict__ meanf, const float* __restrict__ Wi,
                     const float* __restrict__ bi, float* __restrict__ h0) {
    int idx = blockIdx.x * blockDim.x + threadIdx.x;
    if (idx >= B_ * H_) return;
    int b = idx >> 9, h = idx & 511;
    const float* m = meanf + (size_t)b * F_;
    const float* w = Wi + h;
    float a0 = 0.f, a1 = 0.f, a2 = 0.f, a3 = 0.f;
    for (int f = 0; f < F_; f += 4) {
        a0 += m[f + 0] * w[(size_t)(f + 0) * H_];
        a1 += m[f + 1] * w[(size_t)(f + 1) * H_];
        a2 += m[f + 2] * w[(size_t)(f + 2) * H_];
        a3 += m[f + 3] * w[(size_t)(f + 3) * H_];
    }
    h0[idx] = a0 + a1 + a2 + a3 + bi[h];
}

// att1[(b*P+p)*A + a] = sum_f cnn[b,f,p] * W_enc[f,a] + b_enc[a]  (stored bf16)
#define TK_ 32
__global__ void k_att1(const float* __restrict__ cnn, const float* __restrict__ We,
                       const float* __restrict__ be, bf16* __restrict__ att1) {
    __shared__ float As[64][TK_ + 1];
    __shared__ float Bs[TK_][64 + 1];
    int tid = threadIdx.x;
    int row0 = blockIdx.x * 64, col0 = blockIdx.y * 64;
    int tr = tid >> 4, tc = tid & 15;
    float acc[4][4] = {};
    for (int k0 = 0; k0 < F_; k0 += TK_) {
        #pragma unroll
        for (int i = 0; i < 8; ++i) {
            int e = tid + i * 256;
            int r = e & 63, kk = e >> 6;
            int grow = row0 + r;
            int b = grow / P_, p = grow - b * P_;
            As[r][kk] = cnn[((size_t)b * F_ + (k0 + kk)) * P_ + p];
        }
        #pragma unroll
        for (int i = 0; i < 8; ++i) {
            int e = tid + i * 256;
            int c = e & 63, kk = e >> 6;
            Bs[kk][c] = We[(size_t)(k0 + kk) * A_ + col0 + c];
        }
        __syncthreads();
        #pragma unroll
        for (int kk = 0; kk < TK_; ++kk) {
            float av[4], bv[4];
            #pragma unroll
            for (int i = 0; i < 4; ++i) av[i] = As[tr * 4 + i][kk];
            #pragma unroll
            for (int j = 0; j < 4; ++j) bv[j] = Bs[kk][tc * 4 + j];
            #pragma unroll
            for (int i = 0; i < 4; ++i)
                #pragma unroll
                for (int j = 0; j < 4; ++j) acc[i][j] += av[i] * bv[j];
        }
        __syncthreads();
    }
    #pragma unroll
    for (int i = 0; i < 4; ++i) {
        int grow = row0 + tr * 4 + i;
        #pragma unroll
        for (int j = 0; j < 4; ++j) {
            int c = col0 + tc * 4 + j;
            att1[(size_t)grow * A_ + c] = f2b(acc[i][j] + be[c]);
        }
    }
}

// att2[b,a] = h[b,:] @ W_dec[:,a] + b_dec[a]
__global__ void k_att2(const float* __restrict__ h, const float* __restrict__ Wd,
                       const float* __restrict__ bd, float* __restrict__ att2) {
    int idx = blockIdx.x * blockDim.x + threadIdx.x;
    if (idx >= B_ * A_) return;
    int b = idx >> 9, a = idx & 511;
    const float* hr = h + (size_t)b * H_;
    const float* w = Wd + a;
    float a0 = 0.f, a1 = 0.f, a2 = 0.f, a3 = 0.f;
    for (int hh = 0; hh < H_; hh += 4) {
        a0 += hr[hh + 0] * w[(size_t)(hh + 0) * A_];
        a1 += hr[hh + 1] * w[(size_t)(hh + 1) * A_];
        a2 += hr[hh + 2] * w[(size_t)(hh + 2) * A_];
        a3 += hr[hh + 3] * w[(size_t)(hh + 3) * A_];
    }
    att2[idx] = a0 + a1 + a2 + a3 + bd[a];
}

// e[b*P+p] = leaky(att1[b,p,:] + att2[b,:]) @ w_full + b_full
__global__ void k_escore(const bf16* __restrict__ att1, const float* __restrict__ att2,
                         const float* __restrict__ wf, const float* __restrict__ bfull,
                         float* __restrict__ e) {
    int wave = (blockIdx.x * blockDim.x + threadIdx.x) >> 6;
    int lane = threadIdx.x & 63;
    if (wave >= B_ * P_) return;
    int b = wave / P_;
    const bf16* arow = att1 + (size_t)wave * A_;
    const float* a2 = att2 + (size_t)b * A_;
    float acc = 0.f;
    #pragma unroll
    for (int a = lane; a < A_; a += 64) {
        float v = b2f(arow[a]) + a2[a];
        v = v >= 0.f ? v : 0.2f * v;
        acc += v * wf[a];
    }
    acc = wave_reduce(acc);
    if (lane == 0) e[wave] = acc + bfull[0];
}

// softmax over p, write alpha (fp32 ws) and alphas output (fp32)
__global__ void k_softmax(const float* __restrict__ e, float* __restrict__ alpha,
                          float* __restrict__ out_alpha, int t) {
    __shared__ float sdata[256];
    int b = blockIdx.x, tid = threadIdx.x;
    float v = (tid < P_) ? e[b * P_ + tid] : -1e30f;
    sdata[tid] = v;
    __syncthreads();
    for (int s = 128; s; s >>= 1) {
        if (tid < s) sdata[tid] = fmaxf(sdata[tid], sdata[tid + s]);
        __syncthreads();
    }
    float m = sdata[0];
    __syncthreads();
    float ex = (tid < P_) ? expf(v - m) : 0.f;
    sdata[tid] = ex;
    __syncthreads();
    for (int s = 128; s; s >>= 1) {
        if (tid < s) sdata[tid] += sdata[tid + s];
        __syncthreads();
    }
    float inv = 1.f / sdata[0];
    if (tid < P_) {
        float al = ex * inv;
        alpha[b * P_ + tid] = al;
        out_alpha[((size_t)b * T_ + t) * P_ + tid] = al;
    }
}

// attn_feat[b*F+f] = sum_p cnn[b,f,p] * alpha[b,p]
__global__ void k_attnfeat(const float* __restrict__ cnn, const float* __restrict__ alpha,
                           float* __restrict__ af) {
    int wave = (blockIdx.x * blockDim.x + threadIdx.x) >> 6;
    int lane = threadIdx.x & 63;
    if (wave >= B_ * F_) return;
    int b = wave >> 11;
    const float* row = cnn + (size_t)wave * P_;
    const float* al = alpha + b * P_;
    float acc = 0.f;
    for (int p = lane; p < P_; p += 64) acc += row[p] * al[p];
    acc = wave_reduce(acc);
    if (lane == 0) af[wave] = acc;
}

// emb_proj[b,e] = attn_feat[b,:] @ W_embed[:,e] + b_embed[e]
__global__ void k_embproj(const float* __restrict__ af, const float* __restrict__ We,
                          const float* __restrict__ be, float* __restrict__ ep) {
    int idx = blockIdx.x * blockDim.x + threadIdx.x;
    if (idx >= B_ * E_) return;
    int b = idx >> 9, ec = idx & 511;
    const float* a = af + (size_t)b * F_;
    const float* w = We + ec;
    float a0 = 0.f, a1 = 0.f, a2 = 0.f, a3 = 0.f;
    for (int f = 0; f < F_; f += 4) {
        a0 += a[f + 0] * w[(size_t)(f + 0) * E_];
        a1 += a[f + 1] * w[(size_t)(f + 1) * E_];
        a2 += a[f + 2] * w[(size_t)(f + 2) * E_];
        a3 += a[f + 3] * w[(size_t)(f + 3) * E_];
    }
    ep[idx] = a0 + a1 + a2 + a3 + be[ec];
}

// gi[b,j] = [x_t, emb_proj] @ W_ih[j,:] + b_ih[j]; gh[b,j] = h @ W_hh[j,:] + b_hh[j]
__global__ void k_gates(const float* __restrict__ emb, const int* __restrict__ icap,
                        const float* __restrict__ ep, const float* __restrict__ h,
                        const float* __restrict__ Wih, const float* __restrict__ bih,
                        const float* __restrict__ Whh, const float* __restrict__ bhh,
                        float* __restrict__ gi, float* __restrict__ gh, int t) {
    int wave = (blockIdx.x * blockDim.x + threadIdx.x) >> 6;
    int lane = threadIdx.x & 63;
    if (wave >= B_ * 3 * H_) return;
    int b = wave / (3 * H_), j = wave - b * (3 * H_);
    int tok = icap[b * T_ + t];
    const float* xt = emb + (size_t)tok * E_;
    const float* epr = ep + (size_t)b * E_;
    const float* wi = Wih + (size_t)j * (2 * E_);
    float acci = 0.f;
    #pragma unroll
    for (int k = lane; k < 2 * E_; k += 64) {
        float x = (k < E_) ? xt[k] : epr[k - E_];
        acci += x * wi[k];
    }
    const float* hr = h + (size_t)b * H_;
    const float* wh = Whh + (size_t)j * H_;
    float acch = 0.f;
    #pragma unroll
    for (int k = lane; k < H_; k += 64) acch += hr[k] * wh[k];
    acci = wave_reduce(acci);
    acch = wave_reduce(acch);
    if (lane == 0) {
        gi[wave] = acci + bih[j];
        gh[wave] = acch + bhh[j];
    }
}

// GRU combine: h_new = (1-z)*n + z*h
__global__ void k_gru(const float* __restrict__ gi, const float* __restrict__ gh,
                      const float* __restrict__ h, float* __restrict__ hn) {
    int idx = blockIdx.x * blockDim.x + threadIdx.x;
    if (idx >= B_ * H_) return;
    int b = idx >> 9, hh = idx & 511;
    const float* gib = gi + (size_t)b * 3 * H_;
    const float* ghb = gh + (size_t)b * 3 * H_;
    float r = 1.f / (1.f + expf(-(gib[hh] + ghb[hh])));
    float z = 1.f / (1.f + expf(-(gib[H_ + hh] + ghb[H_ + hh])));
    float n = tanhf(gib[2 * H_ + hh] + r * ghb[2 * H_ + hh]);
    hn[idx] = (1.f - z) * n + z * h[idx];
}

// out[(t*B+b)*V + v] = h_new[b,:] @ W_out[:,v] + b_out[v]  (64b x 64v tile, fp32 out)
__global__ void k_out(const float* __restrict__ h, const float* __restrict__ Wo,
                      const float* __restrict__ bo, float* __restrict__ out, int t) {
    __shared__ float hs[64][65];
    __shared__ float ws[64][65];
    int tid = threadIdx.x;
    int v0 = blockIdx.x * 64;
    int tr = tid >> 4, tc = tid & 15;
    float acc[4][4] = {};
    for (int k0 = 0; k0 < H_; k0 += 64) {
        #pragma unroll
        for (int i = 0; i < 16; ++i) {
            int e2 = tid + i * 256;
            int kk = e2 & 63, r = e2 >> 6;
            hs[r][kk] = h[(size_t)r * H_ + k0 + kk];
        }
        #pragma unroll
        for (int i = 0; i < 16; ++i) {
            int e2 = tid + i * 256;
            int c = e2 & 63, kk = e2 >> 6;
            int v = v0 + c;
            ws[kk][c] = (v < V_) ? Wo[(size_t)(k0 + kk) * V_ + v] : 0.f;
        }
        __syncthreads();
        #pragma unroll
        for (int kk = 0; kk < 64; ++kk) {
            float av[4], bv[4];
            #pragma unroll
            for (int i = 0; i < 4; ++i) av[i] = hs[tr * 4 + i][kk];
            #pragma unroll
            for (int j = 0; j < 4; ++j) bv[j] = ws[kk][tc * 4 + j];
            #pragma unroll
            for (int i = 0; i < 4; ++i)
                #pragma unroll
                for (int j = 0; j < 4; ++j) acc[i][j] += av[i] * bv[j];
        }
        __syncthreads();
    }
    #pragma unroll
    for (int i = 0; i < 4; ++i) {
        int b = tr * 4 + i;
        #pragma unroll
        for (int j = 0; j < 4; ++j) {
            int v = v0 + tc * 4 + j;
            if (v < V_) out[((size_t)t * B_ + b) * V_ + v] = acc[i][j] + bo[v];
        }
    }
}

extern "C" void kernel_launch(void* const* d_in, const int* in_sizes, int n_in,
                              void* d_out, int out_size, void* d_ws, size_t ws_size,
                              hipStream_t stream) {
    const float* cnn   = (const float*)d_in[0];
    const int*   icap  = (const int*)d_in[1];   // harness normalizes integers to int32
    // d_in[2] caption_size unused (all == T)
    const float* emb   = (const float*)d_in[3];
    const float* Wenc  = (const float*)d_in[4];
    const float* benc  = (const float*)d_in[5];
    const float* Wdec  = (const float*)d_in[6];
    const float* bdec  = (const float*)d_in[7];
    const float* wfull = (const float*)d_in[8];
    const float* bfull = (const float*)d_in[9];
    const float* Winit = (const float*)d_in[10];
    const float* binit = (const float*)d_in[11];
    const float* Wemb  = (const float*)d_in[12];
    const float* bemb  = (const float*)d_in[13];
    const float* Wih   = (const float*)d_in[14];
    const float* bih   = (const float*)d_in[15];
    const float* Whh   = (const float*)d_in[16];
    const float* bhh   = (const float*)d_in[17];
    const float* Wout  = (const float*)d_in[18];
    const float* bout  = (const float*)d_in[19];

    // Reference outputs are float32 -> d_out is float32 (bf16 label = tolerance mode)
    float* out_pred  = (float*)d_out;
    float* out_alpha = out_pred + (size_t)T_ * B_ * V_;

    char* w = (char*)d_ws;
    float* meanf = (float*)w; w += (size_t)B_ * F_ * 4;
    float* hbuf0 = (float*)w; w += (size_t)B_ * H_ * 4;
    float* hbuf1 = (float*)w; w += (size_t)B_ * H_ * 4;
    float* att2  = (float*)w; w += (size_t)B_ * A_ * 4;
    float* evec  = (float*)w; w += (size_t)B_ * P_ * 4;
    float* alpha = (float*)w; w += (size_t)B_ * P_ * 4;
    float* af    = (float*)w; w += (size_t)B_ * F_ * 4;
    float* ep    = (float*)w; w += (size_t)B_ * E_ * 4;
    float* gi    = (float*)w; w += (size_t)B_ * 3 * H_ * 4;
    float* gh    = (float*)w; w += (size_t)B_ * 3 * H_ * 4;
    bf16*  att1  = (bf16*)w;  // B*P*A bf16 = 12.85 MB

    k_mean<<<B_ * F_ / 4, 256, 0, stream>>>(cnn, meanf);
    k_h0<<<(B_ * H_ + 255) / 256, 256, 0, stream>>>(meanf, Winit, binit, hbuf0);
    k_att1<<<dim3(B_ * P_ / 64, A_ / 64), 256, 0, stream>>>(cnn, Wenc, benc, att1);

    for (int t = 0; t < T_; ++t) {
        const float* hcur = (t & 1) ? hbuf1 : hbuf0;
        float* hnext = (t & 1) ? hbuf0 : hbuf1;

        k_att2<<<(B_ * A_ + 255) / 256, 256, 0, stream>>>(hcur, Wdec, bdec, att2);
        k_escore<<<B_ * P_ / 4, 256, 0, stream>>>(att1, att2, wfull, bfull, evec);
        k_softmax<<<B_, 256, 0, stream>>>(evec, alpha, out_alpha, t);
        k_attnfeat<<<B_ * F_ / 4, 256, 0, stream>>>(cnn, alpha, af);
        k_embproj<<<(B_ * E_ + 255) / 256, 256, 0, stream>>>(af, Wemb, bemb, ep);
        k_gates<<<B_ * 3 * H_ / 4, 256, 0, stream>>>(emb, icap, ep, hcur, Wih, bih,
                                                     Whh, bhh, gi, gh, t);
        k_gru<<<(B_ * H_ + 255) / 256, 256, 0, stream>>>(gi, gh, hcur, hnext);
        k_out<<<(V_ + 63) / 64, 256, 0, stream>>>(hnext, Wout, bout, out_pred, t);
    }
}